// Round 5
// baseline (357.606 us; speedup 1.0000x reference)
//
#include <hip/hip_runtime.h>
#include <stdint.h>
#include <stddef.h>

// FastChannelAttention on MI355X.
//   K0a: zero ssq accumulators
//   K0b: swizzle qkv_w fp32 -> bf16 wl[(c/8)*1536 + j][8]
//   Kxb: x fp32 -> bf16 (row-major), once
//   K1 : qkv = xb @ wl   (256x256 8-phase pipelined bf16 MFMA, counted vmcnt,
//        m201 phase order, NO sched_barrier pinning)
//   K2 : S[b,h] = Q^T K (64x64 Gram over N) + sum-of-squares
//   K3 : attn = softmax(S/(|q||k|) * temp);  M_b = blockdiag(attn)^T @ proj_w
//   K4 : out = V @ M_b + proj_b  (same pipeline, fp32 out)

typedef unsigned short u16;
typedef __attribute__((ext_vector_type(8))) unsigned short u16x8;
typedef __attribute__((ext_vector_type(8))) __bf16 bf16x8;
typedef __attribute__((ext_vector_type(4))) float f32x4;

#define B_DIM 4
#define N_TOK 16384
#define C_DIM 512
#define H_DIM 8
#define CQ3   1536
#define NROWS 65536

__device__ __forceinline__ u16 f2bf(float f) {              // RNE fp32->bf16
  union { float f; uint32_t u; } v; v.f = f;
  uint32_t r = v.u + 0x7FFFu + ((v.u >> 16) & 1u);
  return (u16)(r >> 16);
}
__device__ __forceinline__ float bf2f(u16 u) {
  union { uint32_t u; float f; } v; v.u = ((uint32_t)u) << 16;
  return v.f;
}
__device__ __forceinline__ bf16x8 as_bf16x8(u16x8 u) {
  union { u16x8 u; bf16x8 b; } v; v.u = u; return v.b;
}
__device__ __forceinline__ void gl_lds16(const void* g, void* l) {
  __builtin_amdgcn_global_load_lds(
      (const __attribute__((address_space(1))) uint32_t*)g,
      (__attribute__((address_space(3))) uint32_t*)l, 16, 0, 0);
}

#define VM8 asm volatile("s_waitcnt vmcnt(8)" ::: "memory")
#define VM4 asm volatile("s_waitcnt vmcnt(4)" ::: "memory")
#define VM0 asm volatile("s_waitcnt vmcnt(0)" ::: "memory")
#define NOVM ((void)0)

// Phase (m201 order, unpinned): {ds_read | stage issue | vmcnt?} -> barrier ->
// setprio(1) MFMA setprio(0) -> barrier.  No sched_barrier(0): compiler emits
// fine-grained lgkmcnt between ds_read and dependent MFMA; vmcnt asm carries
// "memory" clobber so load counts at each VM8 are exact; ds/gl_lds ops cannot
// cross the side-effecting s_barrier intrinsic.
// Hazard proof: stage_q overwriting a region read at phase p has q >= p+2,
// issued after barrier2_{p+1}; VM8 at phases 1,3,5,7 guarantees each half-tile
// lands >=1 full barrier before its first reader phase.
#define PH(BUF, KK, MH, VMOP, ...)                                             \
  {                                                                            \
    if ((MH) == 0) {                                                           \
      _Pragma("unroll") for (int nt = 0; nt < 4; ++nt)                         \
        bfr[nt] = *(const bf16x8*)&Bs[(BUF)*16384 + (KK)*8192 + nt*128 + bRd]; \
    }                                                                          \
    bf16x8 af[4];                                                              \
    _Pragma("unroll") for (int mt = 0; mt < 4; ++mt)                           \
      af[mt] = *(const bf16x8*)&As[(BUF)*16384 + (KK)*8192 + (MH)*512 + mt*128 + aRd]; \
    __VA_ARGS__;                                                               \
    VMOP;                                                                      \
    __builtin_amdgcn_s_barrier();                                              \
    __builtin_amdgcn_s_setprio(1);                                             \
    _Pragma("unroll") for (int mt = 0; mt < 4; ++mt)                           \
      _Pragma("unroll") for (int nt = 0; nt < 4; ++nt)                         \
        acc[(MH)*4 + mt][nt] = __builtin_amdgcn_mfma_f32_16x16x32_bf16(        \
            af[mt], bfr[nt], acc[(MH)*4 + mt][nt], 0, 0, 0);                   \
    __builtin_amdgcn_s_setprio(0);                                             \
    __builtin_amdgcn_s_barrier();                                              \
  }

// 256x256 tile, BK=64, 8 waves (2Mx4N), K=512 (8 K-tiles), double-buffered LDS.
// Buffers: [kblk(8)][idx(256)][8] bf16 16B slots (linear for global_load_lds,
// conflict-free ds_read_b128).
template <int BT, int BH, int BJ>
__device__ __forceinline__ void gemm256_pipe(const u16* __restrict__ aSrc,
                                             const u16* __restrict__ bSrc,
                                             int tid, f32x4 (&acc)[8][4],
                                             u16 (&As)[32768], u16 (&Bs)[32768]) {
  const int lane = tid & 63, wid = tid >> 6;
  const int wr = wid >> 2, wc = wid & 3;
  const int aRd = ((lane >> 4) * 256 + wr * 128 + (lane & 15)) * 8;
  const int bRd = ((lane >> 4) * 256 + wc * 64 + (lane & 15)) * 8;
  u16* aD = &As[tid * 8];
  u16* bD = &Bs[tid * 8];

  auto stageA = [&](int t, int h) {
    const u16* s = aSrc + t * 64 + h * 32;
    u16* d = aD + (t & 1) * 16384 + h * 8192;
    gl_lds16(s, d);
    gl_lds16(s + 16, d + 4096);
  };
  auto stageB = [&](int t, int h) {
    const u16* s = bSrc + (size_t)t * BT + h * BH;
    u16* d = bD + (t & 1) * 16384 + h * 8192;
    gl_lds16(s, d);
    gl_lds16(s + BJ, d + 4096);
  };

  bf16x8 bfr[4];
  // prologue: tile0 (4 halves) + tile1 h0  = 12 loads/thread
  stageA(0, 0); stageB(0, 0); stageA(0, 1); stageB(0, 1); stageA(1, 0); stageB(1, 0);
  VM8;                                  // oldest 4 (A00,B00) landed
  __builtin_amdgcn_s_barrier();

  for (int i = 0; i < 3; ++i) {
    const int a = 2 * i, b = 2 * i + 1;
    PH(0, 0, 0, NOVM, stageA(b, 1));
    PH(0, 0, 1, VM8,  stageB(b, 1));
    PH(0, 1, 0, NOVM, stageA(a + 2, 0));
    PH(0, 1, 1, VM8,  stageB(a + 2, 0));
    PH(1, 0, 0, NOVM, stageA(a + 2, 1));
    PH(1, 0, 1, VM8,  stageB(a + 2, 1));
    PH(1, 1, 0, NOVM, stageA(b + 2, 0));
    PH(1, 1, 1, VM8,  stageB(b + 2, 0));
  }
  // epilogue: tiles 6,7
  PH(0, 0, 0, NOVM, stageA(7, 1));
  PH(0, 0, 1, VM8,  stageB(7, 1));
  PH(0, 1, 0, NOVM, );
  PH(0, 1, 1, VM4,  );
  PH(1, 0, 0, NOVM, );
  PH(1, 0, 1, VM0,  );
  PH(1, 1, 0, NOVM, );
  PH(1, 1, 1, NOVM, );
}

// ---------------- K0a: zero ----------------
__global__ void k_zero(float* p, int n) {
  int i = blockIdx.x * 256 + threadIdx.x;
  if (i < n) p[i] = 0.f;
}

// ---------------- K0b: weight swizzle fp32 -> bf16 [(c/8)*1536 + j][8] ----------------
__global__ __launch_bounds__(256) void k_wswz(const float* __restrict__ w, u16* __restrict__ wl) {
  int g = blockIdx.x * 256 + threadIdx.x;       // 0..98303 slots
  int c8 = g / CQ3, j = g - c8 * CQ3;
  u16x8 o;
#pragma unroll
  for (int i = 0; i < 8; ++i) o[i] = f2bf(w[(size_t)(c8 * 8 + i) * CQ3 + j]);
  *(u16x8*)(wl + (size_t)g * 8) = o;
}

// ---------------- Kxb: x fp32 -> bf16 row-major ----------------
__global__ __launch_bounds__(256) void k_xb(const float* __restrict__ x, u16* __restrict__ xb) {
  const int nchunk = NROWS * C_DIM / 8;          // 4194304
  const int stride = 2048 * 256;
  for (int i = blockIdx.x * 256 + threadIdx.x; i < nchunk; i += stride) {
    float4 v0 = *(const float4*)(x + (size_t)i * 8);
    float4 v1 = *(const float4*)(x + (size_t)i * 8 + 4);
    u16x8 o;
    o[0] = f2bf(v0.x); o[1] = f2bf(v0.y); o[2] = f2bf(v0.z); o[3] = f2bf(v0.w);
    o[4] = f2bf(v1.x); o[5] = f2bf(v1.y); o[6] = f2bf(v1.z); o[7] = f2bf(v1.w);
    *(u16x8*)(xb + (size_t)i * 8) = o;
  }
}

// ---------------- K1: QKV GEMM (M=65536, N=1536, K=512), 256^2 8-phase ----------------
__global__ __launch_bounds__(512) void k_qkv(const u16* __restrict__ xb,
                                             const u16* __restrict__ wl,
                                             u16* __restrict__ qkv) {
  __shared__ __align__(16) u16 As[32768];
  __shared__ __align__(16) u16 Bs[32768];
  const int tid = threadIdx.x;
  // bijective XCD swizzle: 1536 wgs = 8 x 192; cb fastest within chunk
  const int orig = blockIdx.x;
  const int wg = (orig & 7) * 192 + (orig >> 3);
  const int cb = wg % 6, rb = wg / 6;
  const int row0 = rb * 256, col0 = cb * 256;
  const u16* aSrc = xb + (size_t)(row0 + (tid & 255)) * C_DIM + (tid >> 8) * 8;
  const u16* bSrc = wl + (tid >> 8) * 12288 + (size_t)(col0 + (tid & 255)) * 8;

  f32x4 acc[8][4];
#pragma unroll
  for (int i = 0; i < 8; ++i)
#pragma unroll
    for (int j = 0; j < 4; ++j) acc[i][j] = (f32x4){0.f, 0.f, 0.f, 0.f};

  gemm256_pipe<98304, 49152, 24576>(aSrc, bSrc, tid, acc, As, Bs);

  // epilogue: wave-private LDS staging (16KB/wave), XOR-swizzled, b128 out
  const int lane = tid & 63, wid = tid >> 6, wr = wid >> 2, wc = wid & 3;
  u16* w = (wid < 4) ? &As[wid * 8192] : &Bs[(wid - 4) * 8192];
#pragma unroll
  for (int mt = 0; mt < 8; ++mt)
#pragma unroll
    for (int nt = 0; nt < 4; ++nt)
#pragma unroll
      for (int r = 0; r < 4; ++r) {
        int row = mt * 16 + (lane >> 4) * 4 + r;
        int col = nt * 16 + (lane & 15);
        int slot = (col >> 3) ^ (row & 7);
        w[row * 64 + slot * 8 + (col & 7)] = f2bf(acc[mt][nt][r]);
      }
  // wave-private: no barrier needed (in-wave LDS ordering via lgkmcnt)
#pragma unroll
  for (int it = 0; it < 16; ++it) {
    int rr = it * 8 + (lane >> 3);
    int slot = (lane & 7) ^ (rr & 7);
    *(u16x8*)&qkv[(size_t)(row0 + wr * 128 + rr) * CQ3 + col0 + wc * 64 + (lane & 7) * 8] =
        *(const u16x8*)&w[rr * 64 + slot * 8];
  }
}

// ---------------- K4: out = V @ M_b + bias (fp32 out), 256^2 8-phase ----------------
__global__ __launch_bounds__(512) void k_out(const u16* __restrict__ qkv,
                                             const u16* __restrict__ Ml,
                                             const float* __restrict__ pb,
                                             float* __restrict__ out) {
  __shared__ __align__(16) u16 As[32768];
  __shared__ __align__(16) u16 Bs[32768];
  const int tid = threadIdx.x;
  // bijective XCD swizzle: 512 wgs = 8 x 64; cb fastest
  const int orig = blockIdx.x;
  const int wg = (orig & 7) * 64 + (orig >> 3);
  const int cb = wg & 1, rb = wg >> 1;
  const int row0 = rb * 256, col0 = cb * 256;    // row0 spans batches (16384 rows each)
  const int b = rb >> 6;
  const u16* aSrc = qkv + (size_t)(row0 + (tid & 255)) * CQ3 + 1024 + (tid >> 8) * 8;
  const u16* bSrc = Ml + (size_t)b * 262144 + (tid >> 8) * 4096 + (size_t)(col0 + (tid & 255)) * 8;

  const int lane = tid & 63, wid = tid >> 6, wr = wid >> 2, wc = wid & 3;
  float bias[4];
#pragma unroll
  for (int nt = 0; nt < 4; ++nt) bias[nt] = pb[col0 + wc * 64 + nt * 16 + (lane & 15)];

  f32x4 acc[8][4];
#pragma unroll
  for (int i = 0; i < 8; ++i)
#pragma unroll
    for (int j = 0; j < 4; ++j) acc[i][j] = (f32x4){0.f, 0.f, 0.f, 0.f};

  gemm256_pipe<32768, 16384, 8192>(aSrc, bSrc, tid, acc, As, Bs);

  // epilogue: fp32, two 64-row halves through wave-private 16KB LDS slice
  float* w = (float*)((wid < 4) ? (void*)&As[wid * 8192] : (void*)&Bs[(wid - 4) * 8192]);
#pragma unroll
  for (int half = 0; half < 2; ++half) {
#pragma unroll
    for (int mt = 0; mt < 4; ++mt)
#pragma unroll
      for (int nt = 0; nt < 4; ++nt)
#pragma unroll
        for (int r = 0; r < 4; ++r) {
          int row = mt * 16 + (lane >> 4) * 4 + r;            // 0..63
          int col = nt * 16 + (lane & 15);
          int slot = (col >> 2) ^ (row & 15);
          w[row * 64 + slot * 4 + (col & 3)] = acc[half * 4 + mt][nt][r] + bias[nt];
        }
#pragma unroll
    for (int it = 0; it < 16; ++it) {
      int rr = it * 4 + (lane >> 4);                          // 0..63
      int s = (lane & 15) ^ (rr & 15);
      *(float4*)&out[(size_t)(row0 + wr * 128 + half * 64 + rr) * C_DIM + col0 + wc * 64 + (lane & 15) * 4] =
          *(const float4*)&w[rr * 64 + s * 4];
    }
  }
}

// ---------------- K2: Gram S[b,h] = Q^T K + sumsq (norms) ----------------
__global__ __launch_bounds__(256) void k_gram(const u16* __restrict__ qkv,
                                              float* __restrict__ Sp,
                                              float* __restrict__ ssq) {
  __shared__ __align__(16) u16 Qs[4][2048];   // [wave][nb2(4)][d(64)][8] bf16
  __shared__ __align__(16) u16 Ks[4][2048];
  __shared__ float Ssh[4096];
  __shared__ float ssqsh[128];
  const int tid = threadIdx.x, lane = tid & 63, wid = tid >> 6;
  const int nblk = blockIdx.x, bh = blockIdx.y;
  const int b = bh >> 3, hh = bh & 7;
  for (int i = tid; i < 4096; i += 256) Ssh[i] = 0.f;
  if (tid < 128) ssqsh[tid] = 0.f;
  __syncthreads();

  f32x4 acc[4][4];
#pragma unroll
  for (int i = 0; i < 4; ++i)
#pragma unroll
    for (int j = 0; j < 4; ++j) acc[i][j] = (f32x4){0.f, 0.f, 0.f, 0.f};
  float sq[8], sk[8];
#pragma unroll
  for (int i = 0; i < 8; ++i) { sq[i] = 0.f; sk[i] = 0.f; }

  const size_t rowbase = (size_t)b * N_TOK + (size_t)nblk * 1024 + wid * 256;
  const int colq = hh * 64;

  for (int it = 0; it < 8; ++it) {
#pragma unroll
    for (int j4 = 0; j4 < 4; ++j4) {
      int idx = j4 * 64 + lane;
      int n = idx >> 3;
      int dd0 = (idx & 7) * 8;
      const u16* gq = qkv + (rowbase + it * 32 + n) * CQ3 + colq + dd0;
      u16x8 q8 = *(const u16x8*)gq;
      u16x8 k8 = *(const u16x8*)(gq + C_DIM);
#pragma unroll
      for (int i = 0; i < 8; ++i) {
        float qf = bf2f(q8[i]); sq[i] += qf * qf;
        float kf = bf2f(k8[i]); sk[i] += kf * kf;
      }
      int base = ((n >> 3) * 64 + dd0) * 8 + (n & 7);   // transposed [nb2][d][nin]
#pragma unroll
      for (int i = 0; i < 8; ++i) {
        Qs[wid][base + i * 8] = q8[i];
        Ks[wid][base + i * 8] = k8[i];
      }
    }
    const int krow = lane >> 4;
    bf16x8 aq[4], ak[4];
#pragma unroll
    for (int m = 0; m < 4; ++m) {
      aq[m] = *(const bf16x8*)&Qs[wid][(krow * 64 + m * 16 + (lane & 15)) * 8];
      ak[m] = *(const bf16x8*)&Ks[wid][(krow * 64 + m * 16 + (lane & 15)) * 8];
    }
#pragma unroll
    for (int dm = 0; dm < 4; ++dm)
#pragma unroll
      for (int em = 0; em < 4; ++em)
        acc[dm][em] = __builtin_amdgcn_mfma_f32_16x16x32_bf16(aq[dm], ak[em], acc[dm][em], 0, 0, 0);
  }
#pragma unroll
  for (int dm = 0; dm < 4; ++dm)
#pragma unroll
    for (int em = 0; em < 4; ++em)
#pragma unroll
      for (int r = 0; r < 4; ++r)
        atomicAdd(&Ssh[(dm * 16 + (lane >> 4) * 4 + r) * 64 + em * 16 + (lane & 15)], acc[dm][em][r]);
#pragma unroll
  for (int i = 0; i < 8; ++i) {
    atomicAdd(&ssqsh[(lane & 7) * 8 + i], sq[i]);
    atomicAdd(&ssqsh[64 + (lane & 7) * 8 + i], sk[i]);
  }
  __syncthreads();
  float* sp = Sp + ((size_t)bh * 16 + nblk) * 4096;
  for (int i = tid; i < 4096; i += 256) sp[i] = Ssh[i];
  if (tid < 128) {
    int c = tid & 63;
    int off = (tid < 64) ? (colq + c) : (C_DIM + colq + c);
    atomicAdd(&ssq[b * 1024 + off], ssqsh[tid]);
  }
}

// ---------------- K3: softmax + fold into proj: M_b[c'=h*64+e][j] ----------------
__global__ __launch_bounds__(256) void k_attn_m(const float* __restrict__ Sp,
                                                const float* __restrict__ ssq,
                                                const float* __restrict__ temp,
                                                const float* __restrict__ pw,
                                                u16* __restrict__ Ml) {
  __shared__ float Ssh[4096];
  __shared__ float rq[64], rk[64];
  const int tid = threadIdx.x, lane = tid & 63, wid = tid >> 6;
  const int bh = blockIdx.x, b = bh >> 3, hh = bh & 7;
#pragma unroll
  for (int t2 = 0; t2 < 16; ++t2) {
    int idx = t2 * 256 + tid;
    float s = 0.f;
#pragma unroll
    for (int p = 0; p < 16; ++p) s += Sp[((size_t)bh * 16 + p) * 4096 + idx];
    Ssh[idx] = s;
  }
  if (tid < 64)
    rq[tid] = 1.f / fmaxf(sqrtf(ssq[b * 1024 + hh * 64 + tid]), 1e-12f);
  else if (tid < 128)
    rk[tid - 64] = 1.f / fmaxf(sqrtf(ssq[b * 1024 + C_DIM + hh * 64 + (tid - 64)]), 1e-12f);
  __syncthreads();
  const float tp = temp[hh];
  const int d = tid >> 2, q4 = tid & 3;
  float vals[16];
  float mx = -3.0e38f;
  const float rqd = rq[d];
#pragma unroll
  for (int i = 0; i < 16; ++i) {
    float v = Ssh[d * 64 + q4 * 16 + i] * rqd * rk[q4 * 16 + i] * tp;
    vals[i] = v; mx = fmaxf(mx, v);
  }
  mx = fmaxf(mx, __shfl_xor(mx, 1));
  mx = fmaxf(mx, __shfl_xor(mx, 2));
  float sum = 0.f;
#pragma unroll
  for (int i = 0; i < 16; ++i) { vals[i] = __expf(vals[i] - mx); sum += vals[i]; }
  sum += __shfl_xor(sum, 1);
  sum += __shfl_xor(sum, 2);
  const float inv = 1.f / sum;
#pragma unroll
  for (int i = 0; i < 16; ++i) Ssh[d * 64 + q4 * 16 + i] = vals[i] * inv;
  __syncthreads();
  f32x4 macc[4][8];
#pragma unroll
  for (int i = 0; i < 4; ++i)
#pragma unroll
    for (int j = 0; j < 8; ++j) macc[i][j] = (f32x4){0.f, 0.f, 0.f, 0.f};
#pragma unroll
  for (int kk = 0; kk < 2; ++kk) {
    bf16x8 af[4], bfr[8];
#pragma unroll
    for (int em = 0; em < 4; ++em) {
      u16x8 t8;
#pragma unroll
      for (int i = 0; i < 8; ++i) {
        int dd = kk * 32 + (lane >> 4) * 8 + i;
        t8[i] = f2bf(Ssh[dd * 64 + em * 16 + (lane & 15)]);
      }
      af[em] = as_bf16x8(t8);
    }
#pragma unroll
    for (int nt = 0; nt < 8; ++nt) {
      int j = wid * 128 + nt * 16 + (lane & 15);
      u16x8 t8;
#pragma unroll
      for (int i = 0; i < 8; ++i) {
        int dd = kk * 32 + (lane >> 4) * 8 + i;
        t8[i] = f2bf(pw[(size_t)(hh * 64 + dd) * C_DIM + j]);
      }
      bfr[nt] = as_bf16x8(t8);
    }
#pragma unroll
    for (int em = 0; em < 4; ++em)
#pragma unroll
      for (int nt = 0; nt < 8; ++nt)
        macc[em][nt] = __builtin_amdgcn_mfma_f32_16x16x32_bf16(af[em], bfr[nt], macc[em][nt], 0, 0, 0);
  }
#pragma unroll
  for (int em = 0; em < 4; ++em)
#pragma unroll
    for (int nt = 0; nt < 8; ++nt) {
      int j = wid * 128 + nt * 16 + (lane & 15);
#pragma unroll
      for (int r = 0; r < 4; ++r) {
        int e = em * 16 + (lane >> 4) * 4 + r;
        int cp = hh * 64 + e;
        Ml[(size_t)b * 262144 + ((size_t)(cp >> 3) * C_DIM + j) * 8 + (cp & 7)] = f2bf(macc[em][nt][r]);
      }
    }
}

extern "C" void kernel_launch(void* const* d_in, const int* in_sizes, int n_in,
                              void* d_out, int out_size, void* d_ws, size_t ws_size,
                              hipStream_t stream) {
  const float* x      = (const float*)d_in[0];
  const float* qkv_w  = (const float*)d_in[3];
  const float* proj_w = (const float*)d_in[4];
  const float* proj_b = (const float*)d_in[5];
  const float* temp   = (const float*)d_in[6];
  float* out = (float*)d_out;

  char* ws = (char*)d_ws;
  const size_t XB_B  = (size_t)NROWS * C_DIM * 2;      // 67108864
  const size_t QKV_B = (size_t)NROWS * CQ3 * 2;        // 201326592
  const size_t WL_B  = (size_t)C_DIM * CQ3 * 2;        // 1572864
  const size_t SP_B  = (size_t)32 * 16 * 4096 * 4;     // 8388608
  const size_t SSQ_B = (size_t)4096 * 4;               // 16384
  u16*   xb  = (u16*)ws;
  u16*   qkv = (u16*)(ws + XB_B);
  u16*   wl  = (u16*)(ws + XB_B + QKV_B);
  float* Sp  = (float*)(ws + XB_B + QKV_B + WL_B);
  float* ssq = (float*)(ws + XB_B + QKV_B + WL_B + SP_B);
  u16*   Ml  = (u16*)(ws + XB_B + QKV_B + WL_B + SP_B + SSQ_B);

  k_zero<<<16, 256, 0, stream>>>(ssq, 4096);
  k_wswz<<<384, 256, 0, stream>>>(qkv_w, wl);
  k_xb<<<2048, 256, 0, stream>>>(x, xb);
  k_qkv<<<1536, 512, 0, stream>>>(xb, wl, qkv);
  k_gram<<<dim3(16, 32), 256, 0, stream>>>(qkv, Sp, ssq);
  k_attn_m<<<32, 256, 0, stream>>>(Sp, ssq, temp, proj_w, Ml);
  k_out<<<512, 512, 0, stream>>>(qkv, Ml, proj_b, out);
}

// Round 6
// 299.013 us; speedup vs baseline: 1.1960x; 1.1960x over previous
//
#include <hip/hip_runtime.h>
#include <stdint.h>
#include <stddef.h>

// FastChannelAttention on MI355X — Gram-refactored pipeline.
//   S[b,h] = Wq_h^T (X_b^T X_b) Wk_h ;  out = X_b (Wv M_b) + bias
//   k_wswz : qkv_w -> wl slots [(c/8)*1536+j][8] bf16   (B-operand form)
//   k_pswz : proj_w -> pwl slots [(d/8)*512+j][8] bf16
//   k_vswz : qkv_w[:,1024:] -> vA row-major bf16 [c][cc] (A-operand form)
//   k_xb   : x -> xb bf16 row-major
//   k_xt2  : x -> xbT bf16 [b][512][16384]
//   k_g    : Gp[kc][b] = partial X^T X (256^2 tiles, 16 K-chunks, 8-phase pipe)
//   k_red  : G[b] = sum_kc Gp (bf16)
//   k_gq   : Gqk[b] = G @ [Wq|Wk]  (direct small GEMM, slot-form output)
//   k_s2   : per (b,h): S, ssq, softmax, M -> Ml slots
//   k_p    : Pl[b] = Wv @ Ml (slot-form)
//   k_out  : out = xb @ Pl + bias (fp32)

typedef unsigned short u16;
typedef __attribute__((ext_vector_type(8))) unsigned short u16x8;
typedef __attribute__((ext_vector_type(8))) __bf16 bf16x8;
typedef __attribute__((ext_vector_type(4))) float f32x4;

#define B_DIM 4
#define N_TOK 16384
#define C_DIM 512
#define CQ3   1536
#define NROWS 65536

__device__ __forceinline__ u16 f2bf(float f) {              // RNE fp32->bf16
  union { float f; uint32_t u; } v; v.f = f;
  uint32_t r = v.u + 0x7FFFu + ((v.u >> 16) & 1u);
  return (u16)(r >> 16);
}
__device__ __forceinline__ float bf2f(u16 u) {
  union { uint32_t u; float f; } v; v.u = ((uint32_t)u) << 16;
  return v.f;
}
__device__ __forceinline__ bf16x8 as_bf16x8(u16x8 u) {
  union { u16x8 u; bf16x8 b; } v; v.u = u; return v.b;
}
__device__ __forceinline__ bf16x8 ldfrag(const u16* p) {
  return as_bf16x8(*(const u16x8*)p);
}
__device__ __forceinline__ void gl_lds16(const void* g, void* l) {
  __builtin_amdgcn_global_load_lds(
      (const __attribute__((address_space(1))) uint32_t*)g,
      (__attribute__((address_space(3))) uint32_t*)l, 16, 0, 0);
}

#define VM8 asm volatile("s_waitcnt vmcnt(8)" ::: "memory")
#define VM4 asm volatile("s_waitcnt vmcnt(4)" ::: "memory")
#define VM0 asm volatile("s_waitcnt vmcnt(0)" ::: "memory")
#define NOVM ((void)0)

#define PH(BUF, KK, MH, VMOP, ...)                                             \
  {                                                                            \
    if ((MH) == 0) {                                                           \
      _Pragma("unroll") for (int nt = 0; nt < 4; ++nt)                         \
        bfr[nt] = *(const bf16x8*)&Bs[(BUF)*16384 + (KK)*8192 + nt*128 + bRd]; \
    }                                                                          \
    bf16x8 af[4];                                                              \
    _Pragma("unroll") for (int mt = 0; mt < 4; ++mt)                           \
      af[mt] = *(const bf16x8*)&As[(BUF)*16384 + (KK)*8192 + (MH)*512 + mt*128 + aRd]; \
    __VA_ARGS__;                                                               \
    VMOP;                                                                      \
    __builtin_amdgcn_s_barrier();                                              \
    __builtin_amdgcn_s_setprio(1);                                             \
    _Pragma("unroll") for (int mt = 0; mt < 4; ++mt)                           \
      _Pragma("unroll") for (int nt = 0; nt < 4; ++nt)                         \
        acc[(MH)*4 + mt][nt] = __builtin_amdgcn_mfma_f32_16x16x32_bf16(        \
            af[mt], bfr[nt], acc[(MH)*4 + mt][nt], 0, 0, 0);                   \
    __builtin_amdgcn_s_setprio(0);                                             \
    __builtin_amdgcn_s_barrier();                                              \
  }

// 256x256 tile, BK=64, 8 waves, NT K-tiles, double-buffered LDS, counted vmcnt.
template <int NT, int AT, int AH, int AJ, int BT, int BH, int BJ>
__device__ __forceinline__ void gemm256_pipe(const u16* __restrict__ aSrc,
                                             const u16* __restrict__ bSrc,
                                             int tid, f32x4 (&acc)[8][4],
                                             u16 (&As)[32768], u16 (&Bs)[32768]) {
  const int lane = tid & 63, wid = tid >> 6;
  const int wr = wid >> 2, wc = wid & 3;
  const int aRd = ((lane >> 4) * 256 + wr * 128 + (lane & 15)) * 8;
  const int bRd = ((lane >> 4) * 256 + wc * 64 + (lane & 15)) * 8;
  u16* aD = &As[tid * 8];
  u16* bD = &Bs[tid * 8];

  auto stageA = [&](int t, int h) {
    const u16* s = aSrc + (size_t)t * AT + h * AH;
    u16* d = aD + (t & 1) * 16384 + h * 8192;
    gl_lds16(s, d);
    gl_lds16(s + AJ, d + 4096);
  };
  auto stageB = [&](int t, int h) {
    const u16* s = bSrc + (size_t)t * BT + h * BH;
    u16* d = bD + (t & 1) * 16384 + h * 8192;
    gl_lds16(s, d);
    gl_lds16(s + BJ, d + 4096);
  };

  bf16x8 bfr[4];
  stageA(0, 0); stageB(0, 0); stageA(0, 1); stageB(0, 1); stageA(1, 0); stageB(1, 0);
  VM8;
  __builtin_amdgcn_s_barrier();

  for (int i = 0; i < NT / 2 - 1; ++i) {
    const int a = 2 * i, b = 2 * i + 1;
    PH(0, 0, 0, NOVM, stageA(b, 1));
    PH(0, 0, 1, VM8,  stageB(b, 1));
    PH(0, 1, 0, NOVM, stageA(a + 2, 0));
    PH(0, 1, 1, VM8,  stageB(a + 2, 0));
    PH(1, 0, 0, NOVM, stageA(a + 2, 1));
    PH(1, 0, 1, VM8,  stageB(a + 2, 1));
    PH(1, 1, 0, NOVM, stageA(b + 2, 0));
    PH(1, 1, 1, VM8,  stageB(b + 2, 0));
  }
  PH(0, 0, 0, NOVM, stageA(NT - 1, 1));
  PH(0, 0, 1, VM8,  stageB(NT - 1, 1));
  PH(0, 1, 0, NOVM, );
  PH(0, 1, 1, VM4,  );
  PH(1, 0, 0, NOVM, );
  PH(1, 0, 1, VM0,  );
  PH(1, 1, 0, NOVM, );
  PH(1, 1, 1, NOVM, );
}

// ---------------- weight prep ----------------
__global__ __launch_bounds__(256) void k_wswz(const float* __restrict__ w, u16* __restrict__ wl) {
  int g = blockIdx.x * 256 + threadIdx.x;       // 98304 slots
  int c8 = g / CQ3, j = g - c8 * CQ3;
  u16x8 o;
#pragma unroll
  for (int i = 0; i < 8; ++i) o[i] = f2bf(w[(size_t)(c8 * 8 + i) * CQ3 + j]);
  *(u16x8*)(wl + (size_t)g * 8) = o;
}
__global__ __launch_bounds__(256) void k_pswz(const float* __restrict__ w, u16* __restrict__ pwl) {
  int g = blockIdx.x * 256 + threadIdx.x;       // 32768 slots
  int d8 = g >> 9, j = g & 511;
  u16x8 o;
#pragma unroll
  for (int i = 0; i < 8; ++i) o[i] = f2bf(w[(size_t)(d8 * 8 + i) * 512 + j]);
  *(u16x8*)(pwl + (size_t)g * 8) = o;
}
__global__ __launch_bounds__(256) void k_vswz(const float* __restrict__ w, u16* __restrict__ vA) {
  int g = blockIdx.x * 256 + threadIdx.x;       // 32768 chunks: c = g>>6, q = g&63
  int c = g >> 6, q = g & 63;
  const float* s = w + (size_t)c * CQ3 + 1024 + q * 8;
  float4 v0 = *(const float4*)s, v1 = *(const float4*)(s + 4);
  u16x8 o;
  o[0] = f2bf(v0.x); o[1] = f2bf(v0.y); o[2] = f2bf(v0.z); o[3] = f2bf(v0.w);
  o[4] = f2bf(v1.x); o[5] = f2bf(v1.y); o[6] = f2bf(v1.z); o[7] = f2bf(v1.w);
  *(u16x8*)(vA + (size_t)g * 8) = o;
}

// ---------------- x conversions ----------------
__global__ __launch_bounds__(256) void k_xb(const float* __restrict__ x, u16* __restrict__ xb) {
  const int nchunk = NROWS * C_DIM / 8;
  const int stride = 2048 * 256;
  for (int i = blockIdx.x * 256 + threadIdx.x; i < nchunk; i += stride) {
    float4 v0 = *(const float4*)(x + (size_t)i * 8);
    float4 v1 = *(const float4*)(x + (size_t)i * 8 + 4);
    u16x8 o;
    o[0] = f2bf(v0.x); o[1] = f2bf(v0.y); o[2] = f2bf(v0.z); o[3] = f2bf(v0.w);
    o[4] = f2bf(v1.x); o[5] = f2bf(v1.y); o[6] = f2bf(v1.z); o[7] = f2bf(v1.w);
    *(u16x8*)(xb + (size_t)i * 8) = o;
  }
}
// transpose-convert: xbT[b][c][n].  Block tile: 64 ch x 128 tok; lane = channel.
__global__ __launch_bounds__(256) void k_xt2(const float* __restrict__ x, u16* __restrict__ xbT) {
  const int bi = blockIdx.x;
  const int b = bi >> 10, ct = (bi >> 7) & 7, tt = bi & 127;
  const int c0 = ct * 64, n0 = tt * 128;
  const int lane = threadIdx.x & 63, w = threadIdx.x >> 6;
  const float* src = x + ((size_t)b * N_TOK + n0 + w * 32) * C_DIM + c0 + lane;
  u16x8 o[4];
#pragma unroll
  for (int q = 0; q < 4; ++q)
#pragma unroll
    for (int j = 0; j < 8; ++j)
      o[q][j] = f2bf(src[(size_t)(q * 8 + j) * C_DIM]);
  u16* dst = xbT + ((size_t)b * C_DIM + c0 + lane) * N_TOK + n0 + w * 32;
#pragma unroll
  for (int q = 0; q < 4; ++q)
    *(u16x8*)(dst + q * 8) = o[q];
}

// ---------------- k_g: Gram partials ----------------
__global__ __launch_bounds__(512) void k_g(const u16* __restrict__ xbT, u16* __restrict__ Gp) {
  __shared__ __align__(16) u16 As[32768];
  __shared__ __align__(16) u16 Bs[32768];
  const int tid = threadIdx.x;
  const int bi = blockIdx.x;
  const int kc = bi >> 4, b = (bi >> 2) & 3, dt = (bi >> 1) & 1, et = bi & 1;
  const u16* aSrc = xbT + ((size_t)b * 512 + dt * 256 + (tid & 255)) * N_TOK + kc * 1024 + (tid >> 8) * 8;
  const u16* bSrc = xbT + ((size_t)b * 512 + et * 256 + (tid & 255)) * N_TOK + kc * 1024 + (tid >> 8) * 8;

  f32x4 acc[8][4];
#pragma unroll
  for (int i = 0; i < 8; ++i)
#pragma unroll
    for (int j = 0; j < 4; ++j) acc[i][j] = (f32x4){0.f, 0.f, 0.f, 0.f};

  gemm256_pipe<16, 64, 32, 16, 64, 32, 16>(aSrc, bSrc, tid, acc, As, Bs);

  // bf16 LDS-staged epilogue (rows d, cols e), row-stride 512
  const int lane = tid & 63, wid = tid >> 6, wr = wid >> 2, wc = wid & 3;
  u16* w = (wid < 4) ? &As[wid * 8192] : &Bs[(wid - 4) * 8192];
#pragma unroll
  for (int mt = 0; mt < 8; ++mt)
#pragma unroll
    for (int nt = 0; nt < 4; ++nt)
#pragma unroll
      for (int r = 0; r < 4; ++r) {
        int row = mt * 16 + (lane >> 4) * 4 + r;
        int col = nt * 16 + (lane & 15);
        int slot = (col >> 3) ^ (row & 7);
        w[row * 64 + slot * 8 + (col & 7)] = f2bf(acc[mt][nt][r]);
      }
  u16* gdst = Gp + (size_t)(kc * 4 + b) * 262144;
#pragma unroll
  for (int it = 0; it < 16; ++it) {
    int rr = it * 8 + (lane >> 3);
    int slot = (lane & 7) ^ (rr & 7);
    *(u16x8*)&gdst[(size_t)(dt * 256 + wr * 128 + rr) * 512 + et * 256 + wc * 64 + (lane & 7) * 8] =
        *(const u16x8*)&w[rr * 64 + slot * 8];
  }
}

// ---------------- k_red: G = sum_kc Gp ----------------
__global__ __launch_bounds__(256) void k_red(const u16* __restrict__ Gp, u16* __restrict__ G) {
  int g = blockIdx.x * 256 + threadIdx.x;       // 131072 chunks of 8
  int b = g >> 15;
  size_t off = (size_t)(g & 32767) * 8;
  float s[8];
#pragma unroll
  for (int i = 0; i < 8; ++i) s[i] = 0.f;
  for (int kc = 0; kc < 16; ++kc) {
    u16x8 v = *(const u16x8*)(Gp + (size_t)(kc * 4 + b) * 262144 + off);
#pragma unroll
    for (int i = 0; i < 8; ++i) s[i] += bf2f(v[i]);
  }
  u16x8 o;
#pragma unroll
  for (int i = 0; i < 8; ++i) o[i] = f2bf(s[i]);
  *(u16x8*)(G + (size_t)b * 262144 + off) = o;
}

// ---------------- k_gq: Gqk = G @ [Wq|Wk] (direct, 128x128 tiles) ----------------
__global__ __launch_bounds__(256) void k_gq(const u16* __restrict__ G,
                                            const u16* __restrict__ wl,
                                            u16* __restrict__ Gqk) {
  const int bi = blockIdx.x;                     // 128: b(4) x mt(4) x nt2(8)
  const int b = bi >> 5, mt = (bi >> 3) & 3, nt2 = bi & 7;
  const int m0 = mt * 128, n0 = nt2 * 128;
  const int lane = threadIdx.x & 63, w = threadIdx.x >> 6;
  f32x4 acc[8][2];
#pragma unroll
  for (int i = 0; i < 8; ++i) { acc[i][0] = (f32x4){0,0,0,0}; acc[i][1] = (f32x4){0,0,0,0}; }
  for (int ks = 0; ks < 16; ++ks) {
    bf16x8 bfr[2];
#pragma unroll
    for (int nf = 0; nf < 2; ++nf)
      bfr[nf] = ldfrag(wl + ((size_t)(ks * 4 + (lane >> 4)) * CQ3 + n0 + w * 32 + nf * 16 + (lane & 15)) * 8);
#pragma unroll
    for (int mf = 0; mf < 8; ++mf) {
      bf16x8 af = ldfrag(G + (size_t)b * 262144 + (size_t)(m0 + mf * 16 + (lane & 15)) * 512 + ks * 32 + (lane >> 4) * 8);
#pragma unroll
      for (int nf = 0; nf < 2; ++nf)
        acc[mf][nf] = __builtin_amdgcn_mfma_f32_16x16x32_bf16(af, bfr[nf], acc[mf][nf], 0, 0, 0);
    }
  }
#pragma unroll
  for (int mf = 0; mf < 8; ++mf)
#pragma unroll
    for (int nf = 0; nf < 2; ++nf)
#pragma unroll
      for (int r = 0; r < 4; ++r) {
        int d = m0 + mf * 16 + (lane >> 4) * 4 + r;
        int j = n0 + w * 32 + nf * 16 + (lane & 15);
        Gqk[(size_t)b * 524288 + ((size_t)(d >> 3) * 1024 + j) * 8 + (d & 7)] = f2bf(acc[mf][nf][r]);
      }
}

// ---------------- k_s2: per (b,h) S, ssq, softmax, M ----------------
__global__ __launch_bounds__(256) void k_s2(const u16* __restrict__ Gqk,
                                            const u16* __restrict__ wl,
                                            const u16* __restrict__ pwl,
                                            const float* __restrict__ temp,
                                            u16* __restrict__ Ml) {
  __shared__ float Ssh[4][4096];
  __shared__ u16 At[64 * 72];
  __shared__ float ssqsh[128];
  __shared__ float rqk[128];
  const int tid = threadIdx.x, lane = tid & 63, w = tid >> 6;
  const int bh = blockIdx.x, b = bh >> 3, hh = bh & 7;
  if (tid < 128) ssqsh[tid] = 0.f;

  // phase A: S partials (K-split across 4 waves)
  f32x4 acc[4][4];
#pragma unroll
  for (int i = 0; i < 4; ++i)
#pragma unroll
    for (int j = 0; j < 4; ++j) acc[i][j] = (f32x4){0.f, 0.f, 0.f, 0.f};
  for (int ks = 0; ks < 4; ++ks) {
    const int crow = w * 16 + ks * 4 + (lane >> 4);
    bf16x8 aq[4], bk[4];
#pragma unroll
    for (int mf = 0; mf < 4; ++mf)
      aq[mf] = ldfrag(wl + ((size_t)crow * CQ3 + hh * 64 + mf * 16 + (lane & 15)) * 8);
#pragma unroll
    for (int nf = 0; nf < 4; ++nf)
      bk[nf] = ldfrag(Gqk + (size_t)b * 524288 + ((size_t)crow * 1024 + 512 + hh * 64 + nf * 16 + (lane & 15)) * 8);
#pragma unroll
    for (int mf = 0; mf < 4; ++mf)
#pragma unroll
      for (int nf = 0; nf < 4; ++nf)
        acc[mf][nf] = __builtin_amdgcn_mfma_f32_16x16x32_bf16(aq[mf], bk[nf], acc[mf][nf], 0, 0, 0);
  }
#pragma unroll
  for (int mf = 0; mf < 4; ++mf)
#pragma unroll
    for (int nf = 0; nf < 4; ++nf)
#pragma unroll
      for (int r = 0; r < 4; ++r)
        Ssh[w][(mf * 16 + (lane >> 4) * 4 + r) * 64 + nf * 16 + (lane & 15)] = acc[mf][nf][r];
  __syncthreads();
  for (int idx = tid; idx < 4096; idx += 256)
    Ssh[0][idx] = Ssh[0][idx] + Ssh[1][idx] + Ssh[2][idx] + Ssh[3][idx];

  // phase B: ssq via diag(Wq^T Gq), diag(Wk^T Gk)
  {
    const int d = tid & 63, part = tid >> 6;
    float sq = 0.f, sk = 0.f;
    for (int co = 0; co < 16; ++co) {
      int c8 = part * 16 + co;
      u16x8 wq = *(const u16x8*)(wl + ((size_t)c8 * CQ3 + hh * 64 + d) * 8);
      u16x8 gq = *(const u16x8*)(Gqk + (size_t)b * 524288 + ((size_t)c8 * 1024 + hh * 64 + d) * 8);
      u16x8 wk = *(const u16x8*)(wl + ((size_t)c8 * CQ3 + 512 + hh * 64 + d) * 8);
      u16x8 gk = *(const u16x8*)(Gqk + (size_t)b * 524288 + ((size_t)c8 * 1024 + 512 + hh * 64 + d) * 8);
#pragma unroll
      for (int i = 0; i < 8; ++i) {
        sq += bf2f(wq[i]) * bf2f(gq[i]);
        sk += bf2f(wk[i]) * bf2f(gk[i]);
      }
    }
    atomicAdd(&ssqsh[d], sq);
    atomicAdd(&ssqsh[64 + d], sk);
  }
  __syncthreads();
  if (tid < 128) rqk[tid] = 1.f / fmaxf(sqrtf(fmaxf(ssqsh[tid], 0.f)), 1e-12f);
  __syncthreads();

  // phase C: softmax rows d (4 threads/row), write attn^T to At
  {
    const float tp = temp[hh];
    const int d = tid >> 2, q4 = tid & 3;
    float vals[16];
    float mx = -3.0e38f;
    const float rqd = rqk[d];
#pragma unroll
    for (int i = 0; i < 16; ++i) {
      float v = Ssh[0][d * 64 + q4 * 16 + i] * rqd * rqk[64 + q4 * 16 + i] * tp;
      vals[i] = v; mx = fmaxf(mx, v);
    }
    mx = fmaxf(mx, __shfl_xor(mx, 1));
    mx = fmaxf(mx, __shfl_xor(mx, 2));
    float sum = 0.f;
#pragma unroll
    for (int i = 0; i < 16; ++i) { vals[i] = __expf(vals[i] - mx); sum += vals[i]; }
    sum += __shfl_xor(sum, 1);
    sum += __shfl_xor(sum, 2);
    const float inv = 1.f / sum;
#pragma unroll
    for (int i = 0; i < 16; ++i) At[(q4 * 16 + i) * 72 + d] = f2bf(vals[i] * inv);
  }
  __syncthreads();

  // phase D: M[e,j] = sum_d attnT[e,d] * pw[h64+d, j]; wave owns j-strip 128
  f32x4 acc2[4][8];
#pragma unroll
  for (int i = 0; i < 4; ++i)
#pragma unroll
    for (int j = 0; j < 8; ++j) acc2[i][j] = (f32x4){0.f, 0.f, 0.f, 0.f};
#pragma unroll
  for (int s = 0; s < 2; ++s) {
    bf16x8 af[4], bfr[8];
#pragma unroll
    for (int mf = 0; mf < 4; ++mf)
      af[mf] = *(const bf16x8*)&At[(mf * 16 + (lane & 15)) * 72 + s * 32 + (lane >> 4) * 8];
#pragma unroll
    for (int nf = 0; nf < 8; ++nf)
      bfr[nf] = ldfrag(pwl + ((size_t)(hh * 8 + s * 4 + (lane >> 4)) * 512 + w * 128 + nf * 16 + (lane & 15)) * 8);
#pragma unroll
    for (int mf = 0; mf < 4; ++mf)
#pragma unroll
      for (int nf = 0; nf < 8; ++nf)
        acc2[mf][nf] = __builtin_amdgcn_mfma_f32_16x16x32_bf16(af[mf], bfr[nf], acc2[mf][nf], 0, 0, 0);
  }
#pragma unroll
  for (int mf = 0; mf < 4; ++mf)
#pragma unroll
    for (int nf = 0; nf < 8; ++nf)
#pragma unroll
      for (int r = 0; r < 4; ++r) {
        int e = mf * 16 + (lane >> 4) * 4 + r;
        int j = w * 128 + nf * 16 + (lane & 15);
        int cc = hh * 64 + e;
        Ml[(size_t)b * 262144 + ((size_t)(cc >> 3) * 512 + j) * 8 + (cc & 7)] = f2bf(acc2[mf][nf][r]);
      }
}

// ---------------- k_p: Pl = Wv @ Ml (direct, 128x128 tiles) ----------------
__global__ __launch_bounds__(256) void k_p(const u16* __restrict__ vA,
                                           const u16* __restrict__ Ml,
                                           u16* __restrict__ Pl) {
  const int bi = blockIdx.x;                     // 64: b(4) x ct(4) x jt(4)
  const int b = bi >> 4, ct = (bi >> 2) & 3, jt = bi & 3;
  const int m0 = ct * 128, j0 = jt * 128;
  const int lane = threadIdx.x & 63, w = threadIdx.x >> 6;
  f32x4 acc[8][2];
#pragma unroll
  for (int i = 0; i < 8; ++i) { acc[i][0] = (f32x4){0,0,0,0}; acc[i][1] = (f32x4){0,0,0,0}; }
  for (int ks = 0; ks < 16; ++ks) {
    bf16x8 bfr[2];
#pragma unroll
    for (int nf = 0; nf < 2; ++nf)
      bfr[nf] = ldfrag(Ml + (size_t)b * 262144 + ((size_t)(ks * 4 + (lane >> 4)) * 512 + j0 + w * 32 + nf * 16 + (lane & 15)) * 8);
#pragma unroll
    for (int mf = 0; mf < 8; ++mf) {
      // A[c, cc-oct] = vA row-major [c][cc]
      bf16x8 af = ldfrag(vA + (size_t)(m0 + mf * 16 + (lane & 15)) * 512 + ks * 32 + (lane >> 4) * 8);
#pragma unroll
      for (int nf = 0; nf < 2; ++nf)
        acc[mf][nf] = __builtin_amdgcn_mfma_f32_16x16x32_bf16(af, bfr[nf], acc[mf][nf], 0, 0, 0);
    }
  }
#pragma unroll
  for (int mf = 0; mf < 8; ++mf)
#pragma unroll
    for (int nf = 0; nf < 2; ++nf)
#pragma unroll
      for (int r = 0; r < 4; ++r) {
        int c = m0 + mf * 16 + (lane >> 4) * 4 + r;
        int j = j0 + w * 32 + nf * 16 + (lane & 15);
        Pl[(size_t)b * 262144 + ((size_t)(c >> 3) * 512 + j) * 8 + (c & 7)] = f2bf(acc[mf][nf][r]);
      }
}

// ---------------- k_out: out = xb @ Pl + bias (fp32) ----------------
__global__ __launch_bounds__(512) void k_out(const u16* __restrict__ xb,
                                             const u16* __restrict__ Pl,
                                             const float* __restrict__ pb,
                                             float* __restrict__ out) {
  __shared__ __align__(16) u16 As[32768];
  __shared__ __align__(16) u16 Bs[32768];
  const int tid = threadIdx.x;
  const int orig = blockIdx.x;                   // 512 = 8 x 64 bijective swizzle
  const int wg = (orig & 7) * 64 + (orig >> 3);
  const int cb = wg & 1, rb = wg >> 1;
  const int row0 = rb * 256, col0 = cb * 256;
  const int b = rb >> 6;
  const u16* aSrc = xb + (size_t)(row0 + (tid & 255)) * 512 + (tid >> 8) * 8;
  const u16* bSrc = Pl + (size_t)b * 262144 + ((size_t)(tid >> 8) * 512 + col0 + (tid & 255)) * 8;

  const int lane = tid & 63, wid = tid >> 6, wr = wid >> 2, wc = wid & 3;
  float bias[4];
#pragma unroll
  for (int nt = 0; nt < 4; ++nt) bias[nt] = pb[col0 + wc * 64 + nt * 16 + (lane & 15)];

  f32x4 acc[8][4];
#pragma unroll
  for (int i = 0; i < 8; ++i)
#pragma unroll
    for (int j = 0; j < 4; ++j) acc[i][j] = (f32x4){0.f, 0.f, 0.f, 0.f};

  gemm256_pipe<8, 64, 32, 16, 32768, 16384, 8192>(aSrc, bSrc, tid, acc, As, Bs);

  float* w = (float*)((wid < 4) ? (void*)&As[wid * 8192] : (void*)&Bs[(wid - 4) * 8192]);
#pragma unroll
  for (int half = 0; half < 2; ++half) {
#pragma unroll
    for (int mt = 0; mt < 4; ++mt)
#pragma unroll
      for (int nt = 0; nt < 4; ++nt)
#pragma unroll
        for (int r = 0; r < 4; ++r) {
          int row = mt * 16 + (lane >> 4) * 4 + r;
          int col = nt * 16 + (lane & 15);
          int slot = (col >> 2) ^ (row & 15);
          w[row * 64 + slot * 4 + (col & 3)] = acc[half * 4 + mt][nt][r] + bias[nt];
        }
#pragma unroll
    for (int it = 0; it < 16; ++it) {
      int rr = it * 4 + (lane >> 4);
      int s = (lane & 15) ^ (rr & 15);
      *(float4*)&out[(size_t)(row0 + wr * 128 + half * 64 + rr) * 512 + col0 + wc * 64 + (lane & 15) * 4] =
          *(const float4*)&w[rr * 64 + s * 4];
    }
  }
}

extern "C" void kernel_launch(void* const* d_in, const int* in_sizes, int n_in,
                              void* d_out, int out_size, void* d_ws, size_t ws_size,
                              hipStream_t stream) {
  const float* x      = (const float*)d_in[0];
  const float* qkv_w  = (const float*)d_in[3];
  const float* proj_w = (const float*)d_in[4];
  const float* proj_b = (const float*)d_in[5];
  const float* temp   = (const float*)d_in[6];
  float* out = (float*)d_out;

  char* ws = (char*)d_ws;
  u16* xb  = (u16*)(ws);                              // 67108864
  u16* xbT = (u16*)(ws + 67108864);                   // 67108864
  u16* wl  = (u16*)(ws + 134217728);                  // 1572864
  u16* pwl = (u16*)(ws + 135790592);                  // 524288
  u16* vA  = (u16*)(ws + 136314880);                  // 524288
  u16* Gp  = (u16*)(ws + 136839168);                  // 33554432
  u16* G   = (u16*)(ws + 170393600);                  // 2097152
  u16* Gqk = (u16*)(ws + 172490752);                  // 4194304
  u16* Ml  = (u16*)(ws + 176685056);                  // 2097152
  u16* Pl  = (u16*)(ws + 178782208);                  // 2097152

  k_wswz<<<384, 256, 0, stream>>>(qkv_w, wl);
  k_pswz<<<128, 256, 0, stream>>>(proj_w, pwl);
  k_vswz<<<128, 256, 0, stream>>>(qkv_w, vA);
  k_xb<<<2048, 256, 0, stream>>>(x, xb);
  k_xt2<<<4096, 256, 0, stream>>>(x, xbT);
  k_g<<<256, 512, 0, stream>>>(xbT, Gp);
  k_red<<<512, 256, 0, stream>>>(Gp, G);
  k_gq<<<128, 256, 0, stream>>>(G, wl, Gqk);
  k_s2<<<32, 256, 0, stream>>>(Gqk, wl, pwl, temp, Ml);
  k_p<<<64, 256, 0, stream>>>(vA, Ml, Pl);
  k_out<<<512, 512, 0, stream>>>(xb, Pl, proj_b, out);
}

// Round 7
// 270.498 us; speedup vs baseline: 1.3220x; 1.1054x over previous
//
#include <hip/hip_runtime.h>
#include <stdint.h>
#include <stddef.h>

// FastChannelAttention on MI355X — Gram-refactored pipeline.
//   S[b,h] = Wq_h^T (X_b^T X_b) Wk_h ;  out = X_b (Wv M_b) + bias
//   k_wswz : qkv_w -> wl slots [(c/8)*1536+j][8] bf16   (B-operand form)
//   k_pswz : proj_w -> pwl slots [(d/8)*512+j][8] bf16
//   k_vswz : qkv_w[:,1024:] -> vA row-major bf16 [c][cc] (A-operand form)
//   k_xc   : x -> xb (row-major bf16) AND xbT [b][512][16384] (fused, LDS transpose)
//   k_g    : Gp[kc][b] = partial X^T X (256^2 tiles, 16 K-chunks, 8-phase pipe)
//   k_red  : G[b] = sum_kc Gp (bf16)
//   k_gq   : Gqk[b] = G @ [Wq|Wk]  (direct small GEMM, slot-form output)
//   k_s2   : per (b,h): S, ssq, softmax, M -> Ml slots
//   k_p    : Pl[b] = Wv @ Ml (slot-form)
//   k_out  : out = xb @ Pl + bias (fp32), 128^2 tiles, 4 blocks/CU

typedef unsigned short u16;
typedef __attribute__((ext_vector_type(8))) unsigned short u16x8;
typedef __attribute__((ext_vector_type(8))) __bf16 bf16x8;
typedef __attribute__((ext_vector_type(4))) float f32x4;

#define B_DIM 4
#define N_TOK 16384
#define C_DIM 512
#define CQ3   1536
#define NROWS 65536

__device__ __forceinline__ u16 f2bf(float f) {              // RNE fp32->bf16
  union { float f; uint32_t u; } v; v.f = f;
  uint32_t r = v.u + 0x7FFFu + ((v.u >> 16) & 1u);
  return (u16)(r >> 16);
}
__device__ __forceinline__ float bf2f(u16 u) {
  union { uint32_t u; float f; } v; v.u = ((uint32_t)u) << 16;
  return v.f;
}
__device__ __forceinline__ bf16x8 as_bf16x8(u16x8 u) {
  union { u16x8 u; bf16x8 b; } v; v.u = u; return v.b;
}
__device__ __forceinline__ bf16x8 ldfrag(const u16* p) {
  return as_bf16x8(*(const u16x8*)p);
}
__device__ __forceinline__ void gl_lds16(const void* g, void* l) {
  __builtin_amdgcn_global_load_lds(
      (const __attribute__((address_space(1))) uint32_t*)g,
      (__attribute__((address_space(3))) uint32_t*)l, 16, 0, 0);
}

#define VM8 asm volatile("s_waitcnt vmcnt(8)" ::: "memory")
#define VM4 asm volatile("s_waitcnt vmcnt(4)" ::: "memory")
#define VM0 asm volatile("s_waitcnt vmcnt(0)" ::: "memory")
#define NOVM ((void)0)

#define PH(BUF, KK, MH, VMOP, ...)                                             \
  {                                                                            \
    if ((MH) == 0) {                                                           \
      _Pragma("unroll") for (int nt = 0; nt < 4; ++nt)                         \
        bfr[nt] = *(const bf16x8*)&Bs[(BUF)*16384 + (KK)*8192 + nt*128 + bRd]; \
    }                                                                          \
    bf16x8 af[4];                                                              \
    _Pragma("unroll") for (int mt = 0; mt < 4; ++mt)                           \
      af[mt] = *(const bf16x8*)&As[(BUF)*16384 + (KK)*8192 + (MH)*512 + mt*128 + aRd]; \
    __VA_ARGS__;                                                               \
    VMOP;                                                                      \
    __builtin_amdgcn_s_barrier();                                              \
    __builtin_amdgcn_s_setprio(1);                                             \
    _Pragma("unroll") for (int mt = 0; mt < 4; ++mt)                           \
      _Pragma("unroll") for (int nt = 0; nt < 4; ++nt)                         \
        acc[(MH)*4 + mt][nt] = __builtin_amdgcn_mfma_f32_16x16x32_bf16(        \
            af[mt], bfr[nt], acc[(MH)*4 + mt][nt], 0, 0, 0);                   \
    __builtin_amdgcn_s_setprio(0);                                             \
    __builtin_amdgcn_s_barrier();                                              \
  }

// 256x256 tile, BK=64, 8 waves, NT K-tiles, double-buffered LDS, counted vmcnt.
template <int NT, int AT, int AH, int AJ, int BT, int BH, int BJ>
__device__ __forceinline__ void gemm256_pipe(const u16* __restrict__ aSrc,
                                             const u16* __restrict__ bSrc,
                                             int tid, f32x4 (&acc)[8][4],
                                             u16 (&As)[32768], u16 (&Bs)[32768]) {
  const int lane = tid & 63, wid = tid >> 6;
  const int wr = wid >> 2, wc = wid & 3;
  const int aRd = ((lane >> 4) * 256 + wr * 128 + (lane & 15)) * 8;
  const int bRd = ((lane >> 4) * 256 + wc * 64 + (lane & 15)) * 8;
  u16* aD = &As[tid * 8];
  u16* bD = &Bs[tid * 8];

  auto stageA = [&](int t, int h) {
    const u16* s = aSrc + (size_t)t * AT + h * AH;
    u16* d = aD + (t & 1) * 16384 + h * 8192;
    gl_lds16(s, d);
    gl_lds16(s + AJ, d + 4096);
  };
  auto stageB = [&](int t, int h) {
    const u16* s = bSrc + (size_t)t * BT + h * BH;
    u16* d = bD + (t & 1) * 16384 + h * 8192;
    gl_lds16(s, d);
    gl_lds16(s + BJ, d + 4096);
  };

  bf16x8 bfr[4];
  stageA(0, 0); stageB(0, 0); stageA(0, 1); stageB(0, 1); stageA(1, 0); stageB(1, 0);
  VM8;
  __builtin_amdgcn_s_barrier();

  for (int i = 0; i < NT / 2 - 1; ++i) {
    const int a = 2 * i, b = 2 * i + 1;
    PH(0, 0, 0, NOVM, stageA(b, 1));
    PH(0, 0, 1, VM8,  stageB(b, 1));
    PH(0, 1, 0, NOVM, stageA(a + 2, 0));
    PH(0, 1, 1, VM8,  stageB(a + 2, 0));
    PH(1, 0, 0, NOVM, stageA(a + 2, 1));
    PH(1, 0, 1, VM8,  stageB(a + 2, 1));
    PH(1, 1, 0, NOVM, stageA(b + 2, 0));
    PH(1, 1, 1, VM8,  stageB(b + 2, 0));
  }
  PH(0, 0, 0, NOVM, stageA(NT - 1, 1));
  PH(0, 0, 1, VM8,  stageB(NT - 1, 1));
  PH(0, 1, 0, NOVM, );
  PH(0, 1, 1, VM4,  );
  PH(1, 0, 0, NOVM, );
  PH(1, 0, 1, VM0,  );
  PH(1, 1, 0, NOVM, );
  PH(1, 1, 1, NOVM, );
}

// ---------------- weight prep ----------------
__global__ __launch_bounds__(256) void k_wswz(const float* __restrict__ w, u16* __restrict__ wl) {
  int g = blockIdx.x * 256 + threadIdx.x;       // 98304 slots
  int c8 = g / CQ3, j = g - c8 * CQ3;
  u16x8 o;
#pragma unroll
  for (int i = 0; i < 8; ++i) o[i] = f2bf(w[(size_t)(c8 * 8 + i) * CQ3 + j]);
  *(u16x8*)(wl + (size_t)g * 8) = o;
}
__global__ __launch_bounds__(256) void k_pswz(const float* __restrict__ w, u16* __restrict__ pwl) {
  int g = blockIdx.x * 256 + threadIdx.x;       // 32768 slots
  int d8 = g >> 9, j = g & 511;
  u16x8 o;
#pragma unroll
  for (int i = 0; i < 8; ++i) o[i] = f2bf(w[(size_t)(d8 * 8 + i) * 512 + j]);
  *(u16x8*)(pwl + (size_t)g * 8) = o;
}
__global__ __launch_bounds__(256) void k_vswz(const float* __restrict__ w, u16* __restrict__ vA) {
  int g = blockIdx.x * 256 + threadIdx.x;       // 32768 chunks: c = g>>6, q = g&63
  int c = g >> 6, q = g & 63;
  const float* s = w + (size_t)c * CQ3 + 1024 + q * 8;
  float4 v0 = *(const float4*)s, v1 = *(const float4*)(s + 4);
  u16x8 o;
  o[0] = f2bf(v0.x); o[1] = f2bf(v0.y); o[2] = f2bf(v0.z); o[3] = f2bf(v0.w);
  o[4] = f2bf(v1.x); o[5] = f2bf(v1.y); o[6] = f2bf(v1.z); o[7] = f2bf(v1.w);
  *(u16x8*)(vA + (size_t)g * 8) = o;
}

// ---------------- k_xc: fused x -> xb + xbT (128tok x 128ch tiles) ----------------
// LDS tile logical [c_loc 128][chunk 16][8] bf16, physChunk = chunk ^ ((c_loc>>3)&15)
// (conflict-free 16B writes and reads; both phases 2 lanes/bank-window).
__global__ __launch_bounds__(256) void k_xc(const float* __restrict__ x,
                                            u16* __restrict__ xb,
                                            u16* __restrict__ xbT) {
  __shared__ __align__(16) u16 T[16384];
  const int bi = blockIdx.x;                    // 2048 = b(4) x tt(128) x ct(4)
  const int b = bi >> 9, tt = (bi >> 2) & 127, ct = bi & 3;
  const int n0 = tt * 128, c0 = ct * 128;
  const int tid = threadIdx.x;
  const int cb8 = (tid & 15) * 8;               // channel sub-block
  const int tch = tid >> 4;                     // token chunk 0..15
  const float* src = x + (size_t)(b * N_TOK + n0 + tch * 8) * C_DIM + c0 + cb8;
  float v[8][8];
#pragma unroll
  for (int j = 0; j < 8; ++j) {
    float4 a0 = *(const float4*)(src + (size_t)j * C_DIM);
    float4 a1 = *(const float4*)(src + (size_t)j * C_DIM + 4);
    v[j][0] = a0.x; v[j][1] = a0.y; v[j][2] = a0.z; v[j][3] = a0.w;
    v[j][4] = a1.x; v[j][5] = a1.y; v[j][6] = a1.z; v[j][7] = a1.w;
  }
  u16* xbd = xb + (size_t)(b * N_TOK + n0 + tch * 8) * C_DIM + c0 + cb8;
#pragma unroll
  for (int j = 0; j < 8; ++j) {
    u16x8 o;
#pragma unroll
    for (int i = 0; i < 8; ++i) o[i] = f2bf(v[j][i]);
    *(u16x8*)(xbd + (size_t)j * C_DIM) = o;
  }
#pragma unroll
  for (int i = 0; i < 8; ++i) {
    int c_loc = cb8 + i;
    int pc = tch ^ (tid & 15);                  // (c_loc>>3)&15 == tid&15
    u16x8 o;
#pragma unroll
    for (int j = 0; j < 8; ++j) o[j] = f2bf(v[j][i]);
    *(u16x8*)&T[c_loc * 128 + pc * 8] = o;
  }
  __syncthreads();
#pragma unroll
  for (int t = 0; t < 8; ++t) {
    int c_loc = t * 16 + (tid >> 4);
    int lch = tid & 15;
    int pc = lch ^ ((c_loc >> 3) & 15);
    u16x8 o = *(const u16x8*)&T[c_loc * 128 + pc * 8];
    *(u16x8*)&xbT[(size_t)(b * C_DIM + c0 + c_loc) * N_TOK + n0 + lch * 8] = o;
  }
}

// ---------------- k_g: Gram partials ----------------
__global__ __launch_bounds__(512) void k_g(const u16* __restrict__ xbT, u16* __restrict__ Gp) {
  __shared__ __align__(16) u16 As[32768];
  __shared__ __align__(16) u16 Bs[32768];
  const int tid = threadIdx.x;
  const int bi = blockIdx.x;
  const int kc = bi >> 4, b = (bi >> 2) & 3, dt = (bi >> 1) & 1, et = bi & 1;
  const u16* aSrc = xbT + ((size_t)b * 512 + dt * 256 + (tid & 255)) * N_TOK + kc * 1024 + (tid >> 8) * 8;
  const u16* bSrc = xbT + ((size_t)b * 512 + et * 256 + (tid & 255)) * N_TOK + kc * 1024 + (tid >> 8) * 8;

  f32x4 acc[8][4];
#pragma unroll
  for (int i = 0; i < 8; ++i)
#pragma unroll
    for (int j = 0; j < 4; ++j) acc[i][j] = (f32x4){0.f, 0.f, 0.f, 0.f};

  gemm256_pipe<16, 64, 32, 16, 64, 32, 16>(aSrc, bSrc, tid, acc, As, Bs);

  const int lane = tid & 63, wid = tid >> 6, wr = wid >> 2, wc = wid & 3;
  u16* w = (wid < 4) ? &As[wid * 8192] : &Bs[(wid - 4) * 8192];
#pragma unroll
  for (int mt = 0; mt < 8; ++mt)
#pragma unroll
    for (int nt = 0; nt < 4; ++nt)
#pragma unroll
      for (int r = 0; r < 4; ++r) {
        int row = mt * 16 + (lane >> 4) * 4 + r;
        int col = nt * 16 + (lane & 15);
        int slot = (col >> 3) ^ (row & 7);
        w[row * 64 + slot * 8 + (col & 7)] = f2bf(acc[mt][nt][r]);
      }
  u16* gdst = Gp + (size_t)(kc * 4 + b) * 262144;
#pragma unroll
  for (int it = 0; it < 16; ++it) {
    int rr = it * 8 + (lane >> 3);
    int slot = (lane & 7) ^ (rr & 7);
    *(u16x8*)&gdst[(size_t)(dt * 256 + wr * 128 + rr) * 512 + et * 256 + wc * 64 + (lane & 7) * 8] =
        *(const u16x8*)&w[rr * 64 + slot * 8];
  }
}

// ---------------- k_red: G = sum_kc Gp ----------------
__global__ __launch_bounds__(256) void k_red(const u16* __restrict__ Gp, u16* __restrict__ G) {
  int g = blockIdx.x * 256 + threadIdx.x;       // 131072 chunks of 8
  int b = g >> 15;
  size_t off = (size_t)(g & 32767) * 8;
  float s[8];
#pragma unroll
  for (int i = 0; i < 8; ++i) s[i] = 0.f;
  for (int kc = 0; kc < 16; ++kc) {
    u16x8 v = *(const u16x8*)(Gp + (size_t)(kc * 4 + b) * 262144 + off);
#pragma unroll
    for (int i = 0; i < 8; ++i) s[i] += bf2f(v[i]);
  }
  u16x8 o;
#pragma unroll
  for (int i = 0; i < 8; ++i) o[i] = f2bf(s[i]);
  *(u16x8*)(G + (size_t)b * 262144 + off) = o;
}

// ---------------- k_gq: Gqk = G @ [Wq|Wk] ----------------
__global__ __launch_bounds__(256) void k_gq(const u16* __restrict__ G,
                                            const u16* __restrict__ wl,
                                            u16* __restrict__ Gqk) {
  const int bi = blockIdx.x;                     // 128: b(4) x mt(4) x nt2(8)
  const int b = bi >> 5, mt = (bi >> 3) & 3, nt2 = bi & 7;
  const int m0 = mt * 128, n0 = nt2 * 128;
  const int lane = threadIdx.x & 63, w = threadIdx.x >> 6;
  f32x4 acc[8][2];
#pragma unroll
  for (int i = 0; i < 8; ++i) { acc[i][0] = (f32x4){0,0,0,0}; acc[i][1] = (f32x4){0,0,0,0}; }
  for (int ks = 0; ks < 16; ++ks) {
    bf16x8 bfr[2];
#pragma unroll
    for (int nf = 0; nf < 2; ++nf)
      bfr[nf] = ldfrag(wl + ((size_t)(ks * 4 + (lane >> 4)) * CQ3 + n0 + w * 32 + nf * 16 + (lane & 15)) * 8);
#pragma unroll
    for (int mf = 0; mf < 8; ++mf) {
      bf16x8 af = ldfrag(G + (size_t)b * 262144 + (size_t)(m0 + mf * 16 + (lane & 15)) * 512 + ks * 32 + (lane >> 4) * 8);
#pragma unroll
      for (int nf = 0; nf < 2; ++nf)
        acc[mf][nf] = __builtin_amdgcn_mfma_f32_16x16x32_bf16(af, bfr[nf], acc[mf][nf], 0, 0, 0);
    }
  }
#pragma unroll
  for (int mf = 0; mf < 8; ++mf)
#pragma unroll
    for (int nf = 0; nf < 2; ++nf)
#pragma unroll
      for (int r = 0; r < 4; ++r) {
        int d = m0 + mf * 16 + (lane >> 4) * 4 + r;
        int j = n0 + w * 32 + nf * 16 + (lane & 15);
        Gqk[(size_t)b * 524288 + ((size_t)(d >> 3) * 1024 + j) * 8 + (d & 7)] = f2bf(acc[mf][nf][r]);
      }
}

// ---------------- k_s2: per (b,h) S, ssq, softmax, M ----------------
__global__ __launch_bounds__(256) void k_s2(const u16* __restrict__ Gqk,
                                            const u16* __restrict__ wl,
                                            const u16* __restrict__ pwl,
                                            const float* __restrict__ temp,
                                            u16* __restrict__ Ml) {
  __shared__ float Ssh[4][4096];
  __shared__ u16 At[64 * 72];
  __shared__ float ssqsh[128];
  __shared__ float rqk[128];
  const int tid = threadIdx.x, lane = tid & 63, w = tid >> 6;
  const int bh = blockIdx.x, b = bh >> 3, hh = bh & 7;
  if (tid < 128) ssqsh[tid] = 0.f;

  f32x4 acc[4][4];
#pragma unroll
  for (int i = 0; i < 4; ++i)
#pragma unroll
    for (int j = 0; j < 4; ++j) acc[i][j] = (f32x4){0.f, 0.f, 0.f, 0.f};
  for (int ks = 0; ks < 4; ++ks) {
    const int crow = w * 16 + ks * 4 + (lane >> 4);
    bf16x8 aq[4], bk[4];
#pragma unroll
    for (int mf = 0; mf < 4; ++mf)
      aq[mf] = ldfrag(wl + ((size_t)crow * CQ3 + hh * 64 + mf * 16 + (lane & 15)) * 8);
#pragma unroll
    for (int nf = 0; nf < 4; ++nf)
      bk[nf] = ldfrag(Gqk + (size_t)b * 524288 + ((size_t)crow * 1024 + 512 + hh * 64 + nf * 16 + (lane & 15)) * 8);
#pragma unroll
    for (int mf = 0; mf < 4; ++mf)
#pragma unroll
      for (int nf = 0; nf < 4; ++nf)
        acc[mf][nf] = __builtin_amdgcn_mfma_f32_16x16x32_bf16(aq[mf], bk[nf], acc[mf][nf], 0, 0, 0);
  }
#pragma unroll
  for (int mf = 0; mf < 4; ++mf)
#pragma unroll
    for (int nf = 0; nf < 4; ++nf)
#pragma unroll
      for (int r = 0; r < 4; ++r)
        Ssh[w][(mf * 16 + (lane >> 4) * 4 + r) * 64 + nf * 16 + (lane & 15)] = acc[mf][nf][r];
  __syncthreads();
  for (int idx = tid; idx < 4096; idx += 256)
    Ssh[0][idx] = Ssh[0][idx] + Ssh[1][idx] + Ssh[2][idx] + Ssh[3][idx];

  {
    const int d = tid & 63, part = tid >> 6;
    float sq = 0.f, sk = 0.f;
    for (int co = 0; co < 16; ++co) {
      int c8 = part * 16 + co;
      u16x8 wq = *(const u16x8*)(wl + ((size_t)c8 * CQ3 + hh * 64 + d) * 8);
      u16x8 gq = *(const u16x8*)(Gqk + (size_t)b * 524288 + ((size_t)c8 * 1024 + hh * 64 + d) * 8);
      u16x8 wk = *(const u16x8*)(wl + ((size_t)c8 * CQ3 + 512 + hh * 64 + d) * 8);
      u16x8 gk = *(const u16x8*)(Gqk + (size_t)b * 524288 + ((size_t)c8 * 1024 + 512 + hh * 64 + d) * 8);
#pragma unroll
      for (int i = 0; i < 8; ++i) {
        sq += bf2f(wq[i]) * bf2f(gq[i]);
        sk += bf2f(wk[i]) * bf2f(gk[i]);
      }
    }
    atomicAdd(&ssqsh[d], sq);
    atomicAdd(&ssqsh[64 + d], sk);
  }
  __syncthreads();
  if (tid < 128) rqk[tid] = 1.f / fmaxf(sqrtf(fmaxf(ssqsh[tid], 0.f)), 1e-12f);
  __syncthreads();

  {
    const float tp = temp[hh];
    const int d = tid >> 2, q4 = tid & 3;
    float vals[16];
    float mx = -3.0e38f;
    const float rqd = rqk[d];
#pragma unroll
    for (int i = 0; i < 16; ++i) {
      float v = Ssh[0][d * 64 + q4 * 16 + i] * rqd * rqk[64 + q4 * 16 + i] * tp;
      vals[i] = v; mx = fmaxf(mx, v);
    }
    mx = fmaxf(mx, __shfl_xor(mx, 1));
    mx = fmaxf(mx, __shfl_xor(mx, 2));
    float sum = 0.f;
#pragma unroll
    for (int i = 0; i < 16; ++i) { vals[i] = __expf(vals[i] - mx); sum += vals[i]; }
    sum += __shfl_xor(sum, 1);
    sum += __shfl_xor(sum, 2);
    const float inv = 1.f / sum;
#pragma unroll
    for (int i = 0; i < 16; ++i) At[(q4 * 16 + i) * 72 + d] = f2bf(vals[i] * inv);
  }
  __syncthreads();

  f32x4 acc2[4][8];
#pragma unroll
  for (int i = 0; i < 4; ++i)
#pragma unroll
    for (int j = 0; j < 8; ++j) acc2[i][j] = (f32x4){0.f, 0.f, 0.f, 0.f};
#pragma unroll
  for (int s = 0; s < 2; ++s) {
    bf16x8 af[4], bfr[8];
#pragma unroll
    for (int mf = 0; mf < 4; ++mf)
      af[mf] = *(const bf16x8*)&At[(mf * 16 + (lane & 15)) * 72 + s * 32 + (lane >> 4) * 8];
#pragma unroll
    for (int nf = 0; nf < 8; ++nf)
      bfr[nf] = ldfrag(pwl + ((size_t)(hh * 8 + s * 4 + (lane >> 4)) * 512 + w * 128 + nf * 16 + (lane & 15)) * 8);
#pragma unroll
    for (int mf = 0; mf < 4; ++mf)
#pragma unroll
      for (int nf = 0; nf < 8; ++nf)
        acc2[mf][nf] = __builtin_amdgcn_mfma_f32_16x16x32_bf16(af[mf], bfr[nf], acc2[mf][nf], 0, 0, 0);
  }
#pragma unroll
  for (int mf = 0; mf < 4; ++mf)
#pragma unroll
    for (int nf = 0; nf < 8; ++nf)
#pragma unroll
      for (int r = 0; r < 4; ++r) {
        int e = mf * 16 + (lane >> 4) * 4 + r;
        int j = w * 128 + nf * 16 + (lane & 15);
        int cc = hh * 64 + e;
        Ml[(size_t)b * 262144 + ((size_t)(cc >> 3) * 512 + j) * 8 + (cc & 7)] = f2bf(acc2[mf][nf][r]);
      }
}

// ---------------- k_p: Pl = Wv @ Ml ----------------
__global__ __launch_bounds__(256) void k_p(const u16* __restrict__ vA,
                                           const u16* __restrict__ Ml,
                                           u16* __restrict__ Pl) {
  const int bi = blockIdx.x;                     // 64: b(4) x ct(4) x jt(4)
  const int b = bi >> 4, ct = (bi >> 2) & 3, jt = bi & 3;
  const int m0 = ct * 128, j0 = jt * 128;
  const int lane = threadIdx.x & 63, w = threadIdx.x >> 6;
  f32x4 acc[8][2];
#pragma unroll
  for (int i = 0; i < 8; ++i) { acc[i][0] = (f32x4){0,0,0,0}; acc[i][1] = (f32x4){0,0,0,0}; }
  for (int ks = 0; ks < 16; ++ks) {
    bf16x8 bfr[2];
#pragma unroll
    for (int nf = 0; nf < 2; ++nf)
      bfr[nf] = ldfrag(Ml + (size_t)b * 262144 + ((size_t)(ks * 4 + (lane >> 4)) * 512 + j0 + w * 32 + nf * 16 + (lane & 15)) * 8);
#pragma unroll
    for (int mf = 0; mf < 8; ++mf) {
      bf16x8 af = ldfrag(vA + (size_t)(m0 + mf * 16 + (lane & 15)) * 512 + ks * 32 + (lane >> 4) * 8);
#pragma unroll
      for (int nf = 0; nf < 2; ++nf)
        acc[mf][nf] = __builtin_amdgcn_mfma_f32_16x16x32_bf16(af, bfr[nf], acc[mf][nf], 0, 0, 0);
    }
  }
#pragma unroll
  for (int mf = 0; mf < 8; ++mf)
#pragma unroll
    for (int nf = 0; nf < 2; ++nf)
#pragma unroll
      for (int r = 0; r < 4; ++r) {
        int c = m0 + mf * 16 + (lane >> 4) * 4 + r;
        int j = j0 + w * 32 + nf * 16 + (lane & 15);
        Pl[(size_t)b * 262144 + ((size_t)(c >> 3) * 512 + j) * 8 + (c & 7)] = f2bf(acc[mf][nf][r]);
      }
}

// ---------------- k_out: out = xb @ Pl + bias, 128^2 tiles, high occupancy ----------------
__global__ __launch_bounds__(256, 4) void k_out(const u16* __restrict__ xb,
                                                const u16* __restrict__ Pl,
                                                const float* __restrict__ pb,
                                                float* __restrict__ out) {
  __shared__ __align__(16) u16 As[8192];   // [kblk 8][m 128][8]
  __shared__ __align__(16) u16 Bs[8192];
  const int tid = threadIdx.x;
  const int orig = blockIdx.x;                   // 2048 = 8 x 256 bijective swizzle
  const int wg = (orig & 7) * 256 + (orig >> 3);
  const int cb = wg & 3, rb = wg >> 2;
  const int row0 = rb * 128, col0 = cb * 128;
  const int b = rb >> 7;
  const int lane = tid & 63, wid = tid >> 6;
  const int wr = wid >> 1, wc = wid & 1;
  float bias[4];
#pragma unroll
  for (int nt = 0; nt < 4; ++nt) bias[nt] = pb[col0 + wc * 64 + nt * 16 + (lane & 15)];

  f32x4 acc[4][4];
#pragma unroll
  for (int i = 0; i < 4; ++i)
#pragma unroll
    for (int j = 0; j < 4; ++j) acc[i][j] = (f32x4){0.f, 0.f, 0.f, 0.f};

  const u16* pbase = Pl + (size_t)b * 262144;
  for (int kb = 0; kb < 8; ++kb) {
#pragma unroll
    for (int s4 = 0; s4 < 4; ++s4) {
      int slot = s4 * 256 + tid;
      int kblk = slot >> 7, idx = slot & 127;
      gl_lds16(xb + (size_t)(row0 + idx) * C_DIM + kb * 64 + kblk * 8, &As[slot * 8]);
      gl_lds16(pbase + ((size_t)(kb * 8 + kblk) * 512 + col0 + idx) * 8, &Bs[slot * 8]);
    }
    __syncthreads();
#pragma unroll
    for (int kk = 0; kk < 2; ++kk) {
      const int krow = kk * 4 + (lane >> 4);
      bf16x8 af[4], bfr[4];
#pragma unroll
      for (int t = 0; t < 4; ++t)
        af[t] = *(const bf16x8*)&As[(krow * 128 + wr * 64 + t * 16 + (lane & 15)) * 8];
#pragma unroll
      for (int t = 0; t < 4; ++t)
        bfr[t] = *(const bf16x8*)&Bs[(krow * 128 + wc * 64 + t * 16 + (lane & 15)) * 8];
#pragma unroll
      for (int mt = 0; mt < 4; ++mt)
#pragma unroll
        for (int nt = 0; nt < 4; ++nt)
          acc[mt][nt] = __builtin_amdgcn_mfma_f32_16x16x32_bf16(af[mt], bfr[nt], acc[mt][nt], 0, 0, 0);
    }
    __syncthreads();
  }
  // fp32 epilogue via wave-private 8KB LDS slice (2 halves of 32 rows)
  float* slice = (wid < 2) ? (float*)&As[wid * 4096] : (float*)&Bs[(wid - 2) * 4096];
#pragma unroll
  for (int half = 0; half < 2; ++half) {
#pragma unroll
    for (int m2 = 0; m2 < 2; ++m2)
#pragma unroll
      for (int nt = 0; nt < 4; ++nt)
#pragma unroll
        for (int r = 0; r < 4; ++r) {
          int row = m2 * 16 + (lane >> 4) * 4 + r;           // 0..31
          int col = nt * 16 + (lane & 15);
          int slot = (col >> 2) ^ (row & 15);
          slice[row * 64 + slot * 4 + (col & 3)] = acc[half * 2 + m2][nt][r] + bias[nt];
        }
#pragma unroll
    for (int it = 0; it < 8; ++it) {
      int rr = it * 4 + (lane >> 4);                         // 0..31
      int s = (lane & 15) ^ (rr & 15);
      *(float4*)&out[(size_t)(row0 + wr * 64 + half * 32 + rr) * C_DIM + col0 + wc * 64 + (lane & 15) * 4] =
          *(const float4*)&slice[rr * 64 + s * 4];
    }
  }
}

extern "C" void kernel_launch(void* const* d_in, const int* in_sizes, int n_in,
                              void* d_out, int out_size, void* d_ws, size_t ws_size,
                              hipStream_t stream) {
  const float* x      = (const float*)d_in[0];
  const float* qkv_w  = (const float*)d_in[3];
  const float* proj_w = (const float*)d_in[4];
  const float* proj_b = (const float*)d_in[5];
  const float* temp   = (const float*)d_in[6];
  float* out = (float*)d_out;

  char* ws = (char*)d_ws;
  u16* xb  = (u16*)(ws);                              // 67108864
  u16* xbT = (u16*)(ws + 67108864);                   // 67108864
  u16* wl  = (u16*)(ws + 134217728);                  // 1572864
  u16* pwl = (u16*)(ws + 135790592);                  // 524288
  u16* vA  = (u16*)(ws + 136314880);                  // 524288
  u16* Gp  = (u16*)(ws + 136839168);                  // 33554432
  u16* G   = (u16*)(ws + 170393600);                  // 2097152
  u16* Gqk = (u16*)(ws + 172490752);                  // 4194304
  u16* Ml  = (u16*)(ws + 176685056);                  // 2097152
  u16* Pl  = (u16*)(ws + 178782208);                  // 2097152

  k_wswz<<<384, 256, 0, stream>>>(qkv_w, wl);
  k_pswz<<<128, 256, 0, stream>>>(proj_w, pwl);
  k_vswz<<<128, 256, 0, stream>>>(qkv_w, vA);
  k_xc<<<2048, 256, 0, stream>>>(x, xb, xbT);
  k_g<<<256, 512, 0, stream>>>(xbT, Gp);
  k_red<<<512, 256, 0, stream>>>(Gp, G);
  k_gq<<<128, 256, 0, stream>>>(G, wl, Gqk);
  k_s2<<<32, 256, 0, stream>>>(Gqk, wl, pwl, temp, Ml);
  k_p<<<64, 256, 0, stream>>>(vA, Ml, Pl);
  k_out<<<2048, 256, 0, stream>>>(xb, Pl, proj_b, out);
}